// Round 10
// baseline (151.581 us; speedup 1.0000x reference)
//
#include <hip/hip_runtime.h>

// AntiAliasInterpolation2d: depthwise 13x13 Gaussian (separable), stride 4.
// in: (32,3,512,512) fp32 ; w: (3,1,13,13) fp32 ; out: (32,3,128,128) fp32
//
// v10: LINEAR-READ experiment. All prior variants read 1 KB wave segments at
// exact 2048 B row strides (power-of-2) and capped at ~3 TB/s; the harness's
// linear fill/copy hit 6.7 TB/s. Theory: HBM channel aliasing on the 2 KB
// stride. Here TILE_R=4 makes a block's 25 input rows one CONTIGUOUS 50 KB
// span, copied linearly into LDS (wave sweeps 1 KB contiguous, block 50 KB).
// Then: v-conv from LDS (b128, conflict-free) -> regs, polyphase buffer
// aliased over the raw tile (LDS stays 50 KB -> 3 blocks/CU), h-conv, store.

constexpr int CH = 3, H = 512, W = 512;
constexpr int OH = 128, OW = 128;
constexpr int KS = 13, KA = 6, STR = 4;
constexpr int TILE_R = 4;                      // output rows per block
constexpr int IN_ROWS = TILE_R * STR + (KS - STR); // 25 contiguous input rows
constexpr int WCH = W / 4;                     // 128 float4 chunks per row
constexpr int CHUNKS = IN_ROWS * WCH;          // 3200 chunks = 50 KB
constexpr int VBW = OW + 4;                    // padded polyphase width

__global__ __launch_bounds__(256)
void aa_interp_kernel(const float* __restrict__ in,
                      const float* __restrict__ wgt,
                      float* __restrict__ out) {
    __shared__ float4 raw[CHUNKS];             // 50 KB raw tile
    __shared__ float hsh[KS];
    float (*poly)[TILE_R][VBW] = (float (*)[TILE_R][VBW])raw;  // aliased 8.3 KB

    const int nc = blockIdx.y;                 // fused (n, c), 0..95
    const int b  = blockIdx.x;                 // row band 0..31
    const int t  = threadIdx.x;

    // Normalized 1D taps = row sums of the outer-product 2D weight.
    if (t < KS) {
        const float* w2 = wgt + (size_t)(nc % CH) * KS * KS + (size_t)t * KS;
        float s = 0.f;
        #pragma unroll
        for (int j = 0; j < KS; ++j) s += w2[j];
        hsh[t] = s;
    }

    // ---- Phase A: linear 50 KB global -> LDS copy ------------------------
    const int gr0 = 16 * b - KA;               // first input row (may be <0)
    const float4* src = (const float4*)(in + ((size_t)nc * H + gr0) * W);
    if (b != 0 && b != OH / TILE_R - 1) {      // interior: pure linear copy
        #pragma unroll
        for (int i = 0; i < 13; ++i) {
            const int idx = t + 256 * i;
            if (idx < CHUNKS) raw[idx] = src[idx];
        }
    } else {                                   // edge: per-row clamp + mask
        #pragma unroll
        for (int i = 0; i < 13; ++i) {
            const int idx = t + 256 * i;
            if (idx < CHUNKS) {
                const int ir = idx >> 7;
                const int gr = gr0 + ir;
                const int rc = min(max(gr, 0), H - 1);
                float4 v = ((const float4*)(in + ((size_t)nc * H + rc) * W))[idx & 127];
                if (gr != rc) v = make_float4(0.f, 0.f, 0.f, 0.f);
                raw[idx] = v;
            }
        }
    }
    __syncthreads();

    float h[KS];
    #pragma unroll
    for (int k = 0; k < KS; ++k) h[k] = hsh[k];

    // ---- Phase B: vertical conv from LDS, results stay in registers ------
    float4 vacc[2];
    #pragma unroll
    for (int j = 0; j < 2; ++j) {
        const int idx = t + 256 * j;
        const int r   = idx >> 7;              // out-row 0..3
        const int c   = idx & 127;             // chunk column
        float4 a = make_float4(0.f, 0.f, 0.f, 0.f);
        #pragma unroll
        for (int k = 0; k < KS; ++k) {
            const float4 v = raw[(STR * r + k) * WCH + c];
            a.x += h[k] * v.x; a.y += h[k] * v.y;
            a.z += h[k] * v.z; a.w += h[k] * v.w;
        }
        vacc[j] = a;
    }
    __syncthreads();                           // all raw reads done

    // ---- Phase C: write polyphase buffer (overwrites raw) + zero pads ----
    #pragma unroll
    for (int j = 0; j < 2; ++j) {
        const int idx = t + 256 * j;
        const int r   = idx >> 7;
        const int c   = idx & 127;
        poly[0][r][c + 2] = vacc[j].x;
        poly[1][r][c + 2] = vacc[j].y;
        poly[2][r][c + 2] = vacc[j].z;
        poly[3][r][c + 2] = vacc[j].w;
    }
    if (t < 64) {                              // 4 phases x 4 rows x 4 pads
        const int p = t >> 4, r = (t >> 2) & 3, q = t & 3;
        poly[p][r][(q < 2) ? q : 128 + q] = 0.f;   // padded idx {0,1,130,131}
    }
    __syncthreads();

    // ---- Phase D: horizontal conv + coalesced store ----------------------
    // Output col oc, tap k: phase (k+2)&3, padded chunk idx oc + ((k+2)>>2).
    float* op = out + ((size_t)nc * OH + (size_t)TILE_R * b) * OW;
    #pragma unroll
    for (int j = 0; j < 2; ++j) {
        const int idx  = t + 256 * j;
        const int orow = idx >> 7;
        const int oc   = idx & 127;
        float a = 0.f;
        #pragma unroll
        for (int k = 0; k < KS; ++k)
            a += h[k] * poly[(k + 2) & 3][orow][oc + ((k + 2) >> 2)];
        op[orow * OW + oc] = a;
    }
}

extern "C" void kernel_launch(void* const* d_in, const int* in_sizes, int n_in,
                              void* d_out, int out_size, void* d_ws, size_t ws_size,
                              hipStream_t stream) {
    const float* in  = (const float*)d_in[0];
    const float* wgt = (const float*)d_in[1];
    float* out = (float*)d_out;

    dim3 grid(OH / TILE_R, 32 * CH);           // (32, 96) = 3072 blocks
    aa_interp_kernel<<<grid, dim3(256), 0, stream>>>(in, wgt, out);
}

// Round 11
// 145.832 us; speedup vs baseline: 1.0394x; 1.0394x over previous
//
#include <hip/hip_runtime.h>

// AntiAliasInterpolation2d: depthwise 13x13 Gaussian (separable), stride 4.
// in: (32,3,512,512) fp32 ; w: (3,1,13,13) fp32 ; out: (32,3,128,128) fp32
//
// v11 == v5, the best-measured variant (147.3 us bench, best of 10 rounds).
// Fused separable, vertical-first streaming with unconditional loads:
// block = 2 halves x 128 chunk-cols; each half streams 25 branch-free
// float4 loads (edge bands: clamped addr + uniform 0/1 mask) into 4 rolling
// accumulators; one barrier; horizontal pass reads a zero-padded polyphase
// LDS buffer (conflict-free b32, no predication); coalesced stores.
//
// Plateau note (R1-R10): nine structural variants (register staging, bigger
// tiles, un-fused 2-pass, LDS linear copy) all land within ~3% of this
// kernel. The iteration is dominated by harness-mandatory traffic (~400 MB
// ws poison + ~200 MB restore per timed call, both at ~85% HBM peak); the
// kernel's ~41 us slot is insensitive to kernel-side structure.

constexpr int CH = 3, H = 512, W = 512;
constexpr int OH = 128, OW = 128;
constexpr int KS = 13, KA = 6, STR = 4;
constexpr int TILE_R = 8;                      // output rows per block
constexpr int GRP = 4;                         // output rows per half
constexpr int G_ROWS = GRP * STR + (KS - STR); // 25 input rows per half
constexpr int WCH = W / 4;                     // 128 float4 chunks per row
constexpr int VBW = WCH + 4;                   // padded width (2 each side)

template <bool EDGE>
__device__ __forceinline__ void vstream(const float* __restrict__ inp, int base,
                                        int c, const float* __restrict__ h,
                                        float4* __restrict__ acc) {
    #pragma unroll
    for (int ir = 0; ir < G_ROWS; ++ir) {
        int row = base + ir;                   // wave-uniform
        float m = 1.f;
        if (EDGE) {
            const int rc = min(max(row, 0), H - 1);
            m = (row == rc) ? 1.f : 0.f;       // uniform 0/1 mask
            row = rc;
        }
        float4 v = ((const float4*)(inp + (size_t)row * W))[c];  // unconditional
        if (EDGE) { v.x *= m; v.y *= m; v.z *= m; v.w *= m; }
        #pragma unroll
        for (int r = 0; r < GRP; ++r) {
            const int k = ir - STR * r;        // compile-time resolved
            if (0 <= k && k < KS) {
                const float hk = h[k];
                acc[r].x += hk * v.x; acc[r].y += hk * v.y;
                acc[r].z += hk * v.z; acc[r].w += hk * v.w;
            }
        }
    }
}

__global__ __launch_bounds__(256)
void aa_interp_kernel(const float* __restrict__ in,
                      const float* __restrict__ wgt,
                      float* __restrict__ out) {
    __shared__ float hsh[KS];
    __shared__ float vb[STR][TILE_R][VBW];     // polyphase + pad, 16.9 KB

    const int nc  = blockIdx.y;                // fused (n, c), 0..95
    const int bi  = blockIdx.x;                // row-band 0..15
    const int r0  = bi * TILE_R;
    const int tid = threadIdx.x;

    // Normalized 1D taps = row sums of the outer-product 2D weight.
    if (tid < KS) {
        const float* w2 = wgt + (size_t)(nc % CH) * KS * KS + (size_t)tid * KS;
        float s = 0.f;
        #pragma unroll
        for (int j = 0; j < KS; ++j) s += w2[j];
        hsh[tid] = s;
    }
    // Zero the 2-chunk pads on both sides of each (phase, row) line.
    if (tid < 128) {
        const int p    = tid >> 5;
        const int orow = (tid >> 2) & 7;
        const int q    = tid & 3;
        vb[p][orow][(q < 2) ? q : 128 + q] = 0.f;   // padded idx {0,1,130,131}
    }
    __syncthreads();

    float h[KS];
    #pragma unroll
    for (int k = 0; k < KS; ++k) h[k] = hsh[k];

    // ---- Phase 1: vertical stride-4 conv, streaming ----------------------
    const int g = tid >> 7;                    // half 0/1
    const int c = tid & 127;                   // chunk column
    const float* inp = in + (size_t)nc * H * W;
    const int base = 32 * bi + 16 * g - KA;    // half's first input row

    float4 acc[GRP];
    #pragma unroll
    for (int r = 0; r < GRP; ++r) acc[r] = make_float4(0.f, 0.f, 0.f, 0.f);

    if (bi != 0 && bi != (OH / TILE_R - 1))
        vstream<false>(inp, base, c, h, acc);  // interior: branch-free
    else
        vstream<true>(inp, base, c, h, acc);   // edge: clamp + uniform mask

    #pragma unroll
    for (int r = 0; r < GRP; ++r) {            // conflict-free b32 writes
        const int orow = g * GRP + r;
        vb[0][orow][c + 2] = acc[r].x;
        vb[1][orow][c + 2] = acc[r].y;
        vb[2][orow][c + 2] = acc[r].z;
        vb[3][orow][c + 2] = acc[r].w;
    }
    __syncthreads();

    // ---- Phase 2: horizontal stride-4 conv from padded polyphase LDS -----
    // Output col oc, tap k: phase p=(k+2)&3, padded chunk idx oc+((k+2)>>2).
    float* op = out + (size_t)nc * OH * OW + (size_t)r0 * OW;
    #pragma unroll
    for (int i = 0; i < TILE_R * OW / 256; ++i) {   // 4 outputs per thread
        const int idx  = tid + 256 * i;
        const int orow = idx >> 7;
        const int oc   = idx & (OW - 1);
        float a = 0.f;
        #pragma unroll
        for (int k = 0; k < KS; ++k)
            a += h[k] * vb[(k + 2) & 3][orow][oc + ((k + 2) >> 2)];
        op[orow * OW + oc] = a;
    }
}

extern "C" void kernel_launch(void* const* d_in, const int* in_sizes, int n_in,
                              void* d_out, int out_size, void* d_ws, size_t ws_size,
                              hipStream_t stream) {
    const float* in  = (const float*)d_in[0];
    const float* wgt = (const float*)d_in[1];
    float* out = (float*)d_out;

    dim3 grid(OH / TILE_R, 32 * CH);           // (16, 96) = 1536 blocks
    aa_interp_kernel<<<grid, dim3(256), 0, stream>>>(in, wgt, out);
}